// Round 1
// baseline (918.274 us; speedup 1.0000x reference)
//
#include <hip/hip_runtime.h>

typedef unsigned short u16;
typedef unsigned int u32;

#define B_ 2
#define T_ 2048
#define D_ 2048
#define N_ 16
#define H_ 128
#define F_ 64
#define SCALE 0.08838834764831845f

typedef __attribute__((ext_vector_type(8))) __bf16 bf16x8;
typedef __attribute__((ext_vector_type(8))) short s16x8;
typedef __attribute__((ext_vector_type(4))) float f32x4;
typedef __attribute__((ext_vector_type(4))) u16 u16x4;

__device__ inline u16 f2bf(float f) {
    union { float f; u32 u; } v; v.f = f;
    u32 u = v.u;
    u32 r = (u + 0x7FFFu + ((u >> 16) & 1u)) >> 16;
    return (u16)r;
}
__device__ inline float bf2f(u16 h) {
    union { u32 u; float f; } v; v.u = ((u32)h) << 16;
    return v.f;
}
__device__ inline bf16x8 ld8(const u16* p) {
    s16x8 r = *reinterpret_cast<const s16x8*>(p);
    return __builtin_bit_cast(bf16x8, r);
}
__device__ inline f32x4 mfma16(bf16x8 a, bf16x8 b, f32x4 c) {
    return __builtin_amdgcn_mfma_f32_16x16x32_bf16(a, b, c, 0, 0, 0);
}
__device__ inline void gload_lds16(const u16* g, u16* l) {
    __builtin_amdgcn_global_load_lds(
        (const __attribute__((address_space(1))) void*)g,
        (__attribute__((address_space(3))) void*)l, 16, 0, 0);
}

// ---------------- convert f32 -> bf16 (straight) ----------------
__global__ __launch_bounds__(256) void cvt_bf16(const float* __restrict__ in,
                                                u16* __restrict__ out, int n) {
    int i = (blockIdx.x * 256 + threadIdx.x) * 8;
    if (i >= n) return;
    float4 a = *reinterpret_cast<const float4*>(in + i);
    float4 b = *reinterpret_cast<const float4*>(in + i + 4);
    s16x8 o;
    o[0] = (short)f2bf(a.x); o[1] = (short)f2bf(a.y);
    o[2] = (short)f2bf(a.z); o[3] = (short)f2bf(a.w);
    o[4] = (short)f2bf(b.x); o[5] = (short)f2bf(b.y);
    o[6] = (short)f2bf(b.z); o[7] = (short)f2bf(b.w);
    *reinterpret_cast<s16x8*>(out + i) = o;
}

// ---------------- transpose+convert: in[K][Nc] f32 -> out[Nc][K] bf16 ----------------
__global__ __launch_bounds__(256) void transpose_cvt(const float* __restrict__ in,
                                                     u16* __restrict__ out,
                                                     int K, int Nc) {
    __shared__ float tile[64][65];
    int n0 = blockIdx.x * 64, k0 = blockIdx.y * 64;
    int tid = threadIdx.x;
    int rr = tid >> 4;          // 0..15
    int cc = (tid & 15) * 4;    // 0..60
#pragma unroll
    for (int it = 0; it < 4; ++it) {
        int kk = it * 16 + rr;
        float4 v = *reinterpret_cast<const float4*>(in + (size_t)(k0 + kk) * Nc + n0 + cc);
        tile[kk][cc] = v.x; tile[kk][cc + 1] = v.y; tile[kk][cc + 2] = v.z; tile[kk][cc + 3] = v.w;
    }
    __syncthreads();
#pragma unroll
    for (int it = 0; it < 4; ++it) {
        int nn = it * 16 + rr;
        u16x4 o;
#pragma unroll
        for (int j = 0; j < 4; ++j) o[j] = f2bf(tile[cc + j][nn]);
        *reinterpret_cast<u16x4*>(out + (size_t)(n0 + nn) * K + k0 + cc) = o;
    }
}

// ---------------- GEMM: C[M][Nn] = A[M][K] * Bt[Nn][K]^T  (bf16 in, bf16 or f32 out) ----------------
#define BM 128
#define BN 128
#define BKg 32

__global__ __launch_bounds__(256) void gemm_bt(const u16* __restrict__ A,
                                               const u16* __restrict__ Bt,
                                               u16* __restrict__ Cb,
                                               float* __restrict__ Cf,
                                               int M, int Nn, int K, int out_f32) {
    __shared__ __align__(16) u16 As[2][BM * BKg];
    __shared__ __align__(16) u16 Bs[2][BM * BKg];
    const int tid = threadIdx.x;
    const int wave = tid >> 6, lane = tid & 63;
    const int m0 = blockIdx.y * BM, n0 = blockIdx.x * BN;
    const int lrow = lane >> 2, lcol = (lane & 3) * 8;
    const int wr = (wave >> 1) * 64, wc = (wave & 1) * 64;
    const int g = lane >> 4, c0 = lane & 15;

    f32x4 acc[4][4] = {};

    const int NT = K / BKg;

    // stage tile kt into buffer buf
    auto stage = [&](int buf, int kt) {
        const int k0 = kt * BKg;
#pragma unroll
        for (int j = 0; j < 2; ++j) {
            const int c = wave + j * 4;   // chunk 0..7, 16 rows each
            gload_lds16(A + (size_t)(m0 + c * 16 + lrow) * K + k0 + lcol, &As[buf][c * 512]);
            gload_lds16(Bt + (size_t)(n0 + c * 16 + lrow) * K + k0 + lcol, &Bs[buf][c * 512]);
        }
    };

    stage(0, 0);
    __syncthreads();

    for (int t = 0; t < NT; ++t) {
        const int cur = t & 1;
        if (t + 1 < NT) stage(cur ^ 1, t + 1);
        bf16x8 af[4], bfr[4];
#pragma unroll
        for (int i = 0; i < 4; ++i) {
            af[i]  = ld8(&As[cur][(wr + i * 16 + c0) * BKg + g * 8]);
            bfr[i] = ld8(&Bs[cur][(wc + i * 16 + c0) * BKg + g * 8]);
        }
#pragma unroll
        for (int i = 0; i < 4; ++i)
#pragma unroll
            for (int j = 0; j < 4; ++j)
                acc[i][j] = mfma16(af[i], bfr[j], acc[i][j]);
        __syncthreads();
    }

#pragma unroll
    for (int i = 0; i < 4; ++i)
#pragma unroll
        for (int j = 0; j < 4; ++j)
#pragma unroll
            for (int r = 0; r < 4; ++r) {
                int row = m0 + wr + i * 16 + g * 4 + r;
                int col = n0 + wc + j * 16 + c0;
                float v = acc[i][j][r];
                if (out_f32) Cf[(size_t)row * Nn + col] = v;
                else         Cb[(size_t)row * Nn + col] = f2bf(v);
            }
}

// ---------------- RoPE + head-split + V-transpose ----------------
// qkv [B*T][3D] bf16 -> qs [BN][T][H] (q*scale), kr [BN][T][H] (rope), vt [BN][H][T] (rope, transposed)
__global__ __launch_bounds__(256) void rope_split(const u16* __restrict__ qkv,
                                                  const float* __restrict__ cosT,
                                                  const float* __restrict__ sinT,
                                                  u16* __restrict__ qs,
                                                  u16* __restrict__ kr,
                                                  u16* __restrict__ vt) {
    __shared__ u16 vtile[64][129];
    int bi = blockIdx.x;
    int hn = bi >> 5;          // 0..31 = b*16+n
    int tt = bi & 31;
    int b = hn >> 4, n = hn & 15;
    int t0 = tt * 64;
    int tid = threadIdx.x;
    int tl = tid >> 2;          // 0..63 row in tile
    int h0 = (tid & 3) * 32;    // 0,32,64,96
    int t = t0 + tl;
    const u16* row = qkv + ((size_t)(b * T_ + t)) * (3 * D_);

    // q: scale + scatter
#pragma unroll
    for (int u = 0; u < 4; ++u) {
        s16x8 raw = *reinterpret_cast<const s16x8*>(row + n * H_ + h0 + u * 8);
        s16x8 o;
#pragma unroll
        for (int e = 0; e < 8; ++e) o[e] = (short)f2bf(bf2f((u16)raw[e]) * SCALE);
        *reinterpret_cast<s16x8*>(qs + ((size_t)hn * T_ + t) * H_ + h0 + u * 8) = o;
    }

    // cos/sin for this row's 16 freq slots
    float cbuf[16], sbuf[16];
    const float* cr = cosT + (size_t)t * F_ + h0 / 2;
    const float* sr = sinT + (size_t)t * F_ + h0 / 2;
#pragma unroll
    for (int u = 0; u < 4; ++u) {
        float4 c4 = *reinterpret_cast<const float4*>(cr + u * 4);
        float4 s4 = *reinterpret_cast<const float4*>(sr + u * 4);
        cbuf[u * 4 + 0] = c4.x; cbuf[u * 4 + 1] = c4.y; cbuf[u * 4 + 2] = c4.z; cbuf[u * 4 + 3] = c4.w;
        sbuf[u * 4 + 0] = s4.x; sbuf[u * 4 + 1] = s4.y; sbuf[u * 4 + 2] = s4.z; sbuf[u * 4 + 3] = s4.w;
    }

    // k: rope + scatter
#pragma unroll
    for (int u = 0; u < 4; ++u) {
        s16x8 raw = *reinterpret_cast<const s16x8*>(row + D_ + n * H_ + h0 + u * 8);
        s16x8 o;
#pragma unroll
        for (int p = 0; p < 4; ++p) {
            float xr = bf2f((u16)raw[2 * p]), xi = bf2f((u16)raw[2 * p + 1]);
            float cc = cbuf[u * 4 + p], ss = sbuf[u * 4 + p];
            o[2 * p]     = (short)f2bf(xr * cc - xi * ss);
            o[2 * p + 1] = (short)f2bf(xr * ss + xi * cc);
        }
        *reinterpret_cast<s16x8*>(kr + ((size_t)hn * T_ + t) * H_ + h0 + u * 8) = o;
    }

    // v: rope -> LDS tile
#pragma unroll
    for (int u = 0; u < 4; ++u) {
        s16x8 raw = *reinterpret_cast<const s16x8*>(row + 2 * D_ + n * H_ + h0 + u * 8);
#pragma unroll
        for (int p = 0; p < 4; ++p) {
            float xr = bf2f((u16)raw[2 * p]), xi = bf2f((u16)raw[2 * p + 1]);
            float cc = cbuf[u * 4 + p], ss = sbuf[u * 4 + p];
            vtile[tl][h0 + u * 8 + 2 * p]     = f2bf(xr * cc - xi * ss);
            vtile[tl][h0 + u * 8 + 2 * p + 1] = f2bf(xr * ss + xi * cc);
        }
    }
    __syncthreads();

    // transposed write: vt[hn][h][t]
    int hrow = tid >> 1;
    int th = (tid & 1) * 32;
    u16 tmp[32];
#pragma unroll
    for (int i = 0; i < 32; ++i) tmp[i] = vtile[th + i][hrow];
    u16* dst = vt + ((size_t)(hn * H_ + hrow)) * T_ + t0 + th;
#pragma unroll
    for (int u = 0; u < 4; ++u) {
        s16x8 o;
#pragma unroll
        for (int e = 0; e < 8; ++e) o[e] = (short)tmp[u * 8 + e];
        *reinterpret_cast<s16x8*>(dst + u * 8) = o;
    }
}

// ---------------- flash attention (causal) ----------------
// qs [BN][T][H] (pre-scaled), kr [BN][T][H], vt [BN][H][T] -> ob [B*T][D] bf16
__global__ __launch_bounds__(256) void attn_fwd(const u16* __restrict__ qs,
                                                const u16* __restrict__ kr,
                                                const u16* __restrict__ vt,
                                                u16* __restrict__ ob) {
    __shared__ __align__(16) u16 plds[4][16 * 88];
    const int wave = threadIdx.x >> 6, lane = threadIdx.x & 63;
    const int bi = blockIdx.x;
    const int hn = bi >> 5;      // head index b*16+n
    const int qt = bi & 31;      // q tile of 64
    const int q0 = qt * 64 + wave * 16;
    const int g = lane >> 4, c0 = lane & 15;
    const u16* qh = qs + (size_t)hn * T_ * H_;
    const u16* kh = kr + (size_t)hn * T_ * H_;
    const u16* vh = vt + (size_t)hn * H_ * T_;

    // Q fragments (row = q0+c0, k = kf*32 + g*8), held for whole loop
    bf16x8 qf[4];
#pragma unroll
    for (int kf = 0; kf < 4; ++kf)
        qf[kf] = ld8(qh + (size_t)(q0 + c0) * H_ + kf * 32 + g * 8);

    f32x4 o[8] = {};
    float m[4], l[4];
#pragma unroll
    for (int r = 0; r < 4; ++r) { m[r] = -1e30f; l[r] = 0.0f; }

    u16* pw = &plds[wave][0];
    const int kv_end = q0 + 16;   // causal bound for this wave

    for (int kv0 = 0; kv0 < kv_end; kv0 += 64) {
        // ---- S = Q K^T  (16 x 64) ----
        f32x4 s[4] = {};
#pragma unroll
        for (int cc = 0; cc < 4; ++cc) {
#pragma unroll
            for (int kf = 0; kf < 4; ++kf) {
                bf16x8 kfr = ld8(kh + (size_t)(kv0 + cc * 16 + c0) * H_ + kf * 32 + g * 8);
                s[cc] = mfma16(qf[kf], kfr, s[cc]);
            }
        }
        // ---- causal mask ----
        if (kv0 + 63 > q0) {
#pragma unroll
            for (int cc = 0; cc < 4; ++cc) {
                int col = kv0 + cc * 16 + c0;
#pragma unroll
                for (int r = 0; r < 4; ++r) {
                    int rowi = q0 + g * 4 + r;
                    if (col > rowi) s[cc][r] = -1e30f;
                }
            }
        }
        // ---- online softmax ----
        float pm[4];
#pragma unroll
        for (int r = 0; r < 4; ++r) {
            pm[r] = fmaxf(fmaxf(s[0][r], s[1][r]), fmaxf(s[2][r], s[3][r]));
        }
#pragma unroll
        for (int r = 0; r < 4; ++r) {
            pm[r] = fmaxf(pm[r], __shfl_xor(pm[r], 1));
            pm[r] = fmaxf(pm[r], __shfl_xor(pm[r], 2));
            pm[r] = fmaxf(pm[r], __shfl_xor(pm[r], 4));
            pm[r] = fmaxf(pm[r], __shfl_xor(pm[r], 8));
        }
        float al[4], rs[4];
#pragma unroll
        for (int r = 0; r < 4; ++r) {
            float mn = fmaxf(m[r], pm[r]);
            al[r] = __expf(m[r] - mn);
            m[r] = mn;
            rs[r] = 0.0f;
        }
#pragma unroll
        for (int cc = 0; cc < 4; ++cc)
#pragma unroll
            for (int r = 0; r < 4; ++r) {
                float p = __expf(s[cc][r] - m[r]);
                s[cc][r] = p;
                rs[r] += p;
            }
#pragma unroll
        for (int r = 0; r < 4; ++r) {
            rs[r] += __shfl_xor(rs[r], 1);
            rs[r] += __shfl_xor(rs[r], 2);
            rs[r] += __shfl_xor(rs[r], 4);
            rs[r] += __shfl_xor(rs[r], 8);
            l[r] = l[r] * al[r] + rs[r];
        }
#pragma unroll
        for (int hf = 0; hf < 8; ++hf)
#pragma unroll
            for (int r = 0; r < 4; ++r) o[hf][r] *= al[r];

        // ---- P -> LDS (C-layout write), read back in A-layout ----
#pragma unroll
        for (int cc = 0; cc < 4; ++cc)
#pragma unroll
            for (int r = 0; r < 4; ++r)
                pw[(g * 4 + r) * 88 + cc * 16 + c0] = f2bf(s[cc][r]);

        bf16x8 pa[2];
#pragma unroll
        for (int kf2 = 0; kf2 < 2; ++kf2)
            pa[kf2] = ld8(&pw[c0 * 88 + kf2 * 32 + g * 8]);

        // ---- O += P V ----
#pragma unroll
        for (int hf = 0; hf < 8; ++hf) {
#pragma unroll
            for (int kf2 = 0; kf2 < 2; ++kf2) {
                bf16x8 vfr = ld8(vh + (size_t)(hf * 16 + c0) * T_ + kv0 + kf2 * 32 + g * 8);
                o[hf] = mfma16(pa[kf2], vfr, o[hf]);
            }
        }
    }

    // ---- epilogue: normalize, write [B*T][D] bf16 ----
    const int bb = hn >> 4, nn = hn & 15;
    float inv[4];
#pragma unroll
    for (int r = 0; r < 4; ++r) inv[r] = 1.0f / l[r];
#pragma unroll
    for (int hf = 0; hf < 8; ++hf)
#pragma unroll
        for (int r = 0; r < 4; ++r) {
            int t = q0 + g * 4 + r;
            ob[((size_t)(bb * T_ + t)) * D_ + nn * H_ + hf * 16 + c0] = f2bf(o[hf][r] * inv[r]);
        }
}

// ---------------- launch ----------------
extern "C" void kernel_launch(void* const* d_in, const int* in_sizes, int n_in,
                              void* d_out, int out_size, void* d_ws, size_t ws_size,
                              hipStream_t stream) {
    const float* x      = (const float*)d_in[0];
    // d_in[1] = mask (causal tril) -- implemented analytically
    const float* cosT   = (const float*)d_in[2];
    const float* sinT   = (const float*)d_in[3];
    const float* w_attn = (const float*)d_in[4];
    const float* w_out  = (const float*)d_in[5];
    float* out = (float*)d_out;

    char* ws = (char*)d_ws;
    u16* xb  = (u16*)(ws + 0);                  // x bf16            [4096][2048]   16.8MB
    u16* wat = (u16*)(ws + 16777216);           // w_attn^T bf16     [6144][2048]   25.2MB
    u16* wot = (u16*)(ws + 41943040);           // w_out^T bf16      [2048][2048]    8.4MB
    u16* qkv = (u16*)(ws + 50331648);           // qkv bf16          [4096][6144]   50.3MB
    u16* qsb = (u16*)(ws + 100663296);          // q scaled          [32][2048][128]
    u16* krb = (u16*)(ws + 117440512);          // k rope            [32][2048][128]
    u16* vtb = (u16*)(ws + 134217728);          // v rope transposed [32][128][2048]
    u16* obf = (u16*)(ws + 0);                  // attn out bf16 (reuses xb)

    // 1. convert x
    cvt_bf16<<<(B_ * T_ * D_) / (256 * 8), 256, 0, stream>>>(x, xb, B_ * T_ * D_);
    // 2. transpose weights
    transpose_cvt<<<dim3(3 * D_ / 64, D_ / 64), 256, 0, stream>>>(w_attn, wat, D_, 3 * D_);
    transpose_cvt<<<dim3(D_ / 64, D_ / 64), 256, 0, stream>>>(w_out, wot, D_, D_);
    // 3. qkv = x @ w_attn
    gemm_bt<<<dim3(3 * D_ / BN, B_ * T_ / BM), 256, 0, stream>>>(xb, wat, qkv, nullptr,
                                                                 B_ * T_, 3 * D_, D_, 0);
    // 4. rope + head split + v transpose
    rope_split<<<B_ * N_ * (T_ / 64), 256, 0, stream>>>(qkv, cosT, sinT, qsb, krb, vtb);
    // 5. flash attention
    attn_fwd<<<B_ * N_ * (T_ / 64), 256, 0, stream>>>(qsb, krb, vtb, obf);
    // 6. out = o @ w_out
    gemm_bt<<<dim3(D_ / BN, B_ * T_ / BM), 256, 0, stream>>>(obf, wot, nullptr, out,
                                                             B_ * T_, D_, D_, 1);
}

// Round 2
// 369.561 us; speedup vs baseline: 2.4848x; 2.4848x over previous
//
#include <hip/hip_runtime.h>

typedef unsigned short u16;
typedef unsigned int u32;

#define B_ 2
#define T_ 2048
#define D_ 2048
#define N_ 16
#define H_ 128
#define F_ 64
#define SCALE 0.08838834764831845f

typedef __attribute__((ext_vector_type(8))) __bf16 bf16x8;
typedef __attribute__((ext_vector_type(8))) short s16x8;
typedef __attribute__((ext_vector_type(4))) float f32x4;
typedef __attribute__((ext_vector_type(4))) u16 u16x4;

__device__ inline u16 f2bf(float f) {
    union { float f; u32 u; } v; v.f = f;
    u32 u = v.u;
    u32 r = (u + 0x7FFFu + ((u >> 16) & 1u)) >> 16;
    return (u16)r;
}
__device__ inline float bf2f(u16 h) {
    union { u32 u; float f; } v; v.u = ((u32)h) << 16;
    return v.f;
}
__device__ inline bf16x8 ld8(const u16* p) {
    s16x8 r = *reinterpret_cast<const s16x8*>(p);
    return __builtin_bit_cast(bf16x8, r);
}
__device__ inline f32x4 mfma16(bf16x8 a, bf16x8 b, f32x4 c) {
    return __builtin_amdgcn_mfma_f32_16x16x32_bf16(a, b, c, 0, 0, 0);
}
__device__ inline void gload_lds16(const u16* g, u16* l) {
    __builtin_amdgcn_global_load_lds(
        (const __attribute__((address_space(1))) void*)g,
        (__attribute__((address_space(3))) void*)l, 16, 0, 0);
}

// ---------------- convert f32 -> bf16 (straight) ----------------
__global__ __launch_bounds__(256) void cvt_bf16(const float* __restrict__ in,
                                                u16* __restrict__ out, int n) {
    int i = (blockIdx.x * 256 + threadIdx.x) * 8;
    if (i >= n) return;
    float4 a = *reinterpret_cast<const float4*>(in + i);
    float4 b = *reinterpret_cast<const float4*>(in + i + 4);
    s16x8 o;
    o[0] = (short)f2bf(a.x); o[1] = (short)f2bf(a.y);
    o[2] = (short)f2bf(a.z); o[3] = (short)f2bf(a.w);
    o[4] = (short)f2bf(b.x); o[5] = (short)f2bf(b.y);
    o[6] = (short)f2bf(b.z); o[7] = (short)f2bf(b.w);
    *reinterpret_cast<s16x8*>(out + i) = o;
}

// ---------------- transpose+convert: in[K][Nc] f32 -> out[Nc][K] bf16 ----------------
__global__ __launch_bounds__(256) void transpose_cvt(const float* __restrict__ in,
                                                     u16* __restrict__ out,
                                                     int K, int Nc) {
    __shared__ float tile[64][65];
    int n0 = blockIdx.x * 64, k0 = blockIdx.y * 64;
    int tid = threadIdx.x;
    int rr = tid >> 4;          // 0..15
    int cc = (tid & 15) * 4;    // 0..60
#pragma unroll
    for (int it = 0; it < 4; ++it) {
        int kk = it * 16 + rr;
        float4 v = *reinterpret_cast<const float4*>(in + (size_t)(k0 + kk) * Nc + n0 + cc);
        tile[kk][cc] = v.x; tile[kk][cc + 1] = v.y; tile[kk][cc + 2] = v.z; tile[kk][cc + 3] = v.w;
    }
    __syncthreads();
#pragma unroll
    for (int it = 0; it < 4; ++it) {
        int nn = it * 16 + rr;
        u16x4 o;
#pragma unroll
        for (int j = 0; j < 4; ++j) o[j] = f2bf(tile[cc + j][nn]);
        *reinterpret_cast<u16x4*>(out + (size_t)(n0 + nn) * K + k0 + cc) = o;
    }
}

// ---------------- GEMM: C[M][Nn] = A[M][K] * Bt[Nn][K]^T ----------------
#define BM 128
#define BN 128
#define BKg 32

__global__ __launch_bounds__(256) void gemm_bt(const u16* __restrict__ A,
                                               const u16* __restrict__ Bt,
                                               u16* __restrict__ Cb,
                                               float* __restrict__ Cf,
                                               int M, int Nn, int K, int out_f32) {
    __shared__ __align__(16) u16 As[2][BM * BKg];
    __shared__ __align__(16) u16 Bs[2][BM * BKg];
    const int tid = threadIdx.x;
    const int wave = tid >> 6, lane = tid & 63;
    const int m0 = blockIdx.y * BM, n0 = blockIdx.x * BN;
    const int lrow = lane >> 2, lcol = (lane & 3) * 8;
    const int wr = (wave >> 1) * 64, wc = (wave & 1) * 64;
    const int g = lane >> 4, c0 = lane & 15;

    f32x4 acc[4][4] = {};

    const int NT = K / BKg;

    auto stage = [&](int buf, int kt) {
        const int k0 = kt * BKg;
#pragma unroll
        for (int j = 0; j < 2; ++j) {
            const int c = wave + j * 4;
            gload_lds16(A + (size_t)(m0 + c * 16 + lrow) * K + k0 + lcol, &As[buf][c * 512]);
            gload_lds16(Bt + (size_t)(n0 + c * 16 + lrow) * K + k0 + lcol, &Bs[buf][c * 512]);
        }
    };

    stage(0, 0);
    __syncthreads();

    for (int t = 0; t < NT; ++t) {
        const int cur = t & 1;
        if (t + 1 < NT) stage(cur ^ 1, t + 1);
        bf16x8 af[4], bfr[4];
#pragma unroll
        for (int i = 0; i < 4; ++i) {
            af[i]  = ld8(&As[cur][(wr + i * 16 + c0) * BKg + g * 8]);
            bfr[i] = ld8(&Bs[cur][(wc + i * 16 + c0) * BKg + g * 8]);
        }
#pragma unroll
        for (int i = 0; i < 4; ++i)
#pragma unroll
            for (int j = 0; j < 4; ++j)
                acc[i][j] = mfma16(af[i], bfr[j], acc[i][j]);
        __syncthreads();
    }

#pragma unroll
    for (int i = 0; i < 4; ++i)
#pragma unroll
        for (int j = 0; j < 4; ++j)
#pragma unroll
            for (int r = 0; r < 4; ++r) {
                int row = m0 + wr + i * 16 + g * 4 + r;
                int col = n0 + wc + j * 16 + c0;
                float v = acc[i][j][r];
                if (out_f32) Cf[(size_t)row * Nn + col] = v;
                else         Cb[(size_t)row * Nn + col] = f2bf(v);
            }
}

// ---------------- RoPE + head-split + V-transpose ----------------
__global__ __launch_bounds__(256) void rope_split(const u16* __restrict__ qkv,
                                                  const float* __restrict__ cosT,
                                                  const float* __restrict__ sinT,
                                                  u16* __restrict__ qs,
                                                  u16* __restrict__ kr,
                                                  u16* __restrict__ vt) {
    __shared__ u16 vtile[64][129];
    int bi = blockIdx.x;
    int hn = bi >> 5;
    int tt = bi & 31;
    int b = hn >> 4, n = hn & 15;
    int t0 = tt * 64;
    int tid = threadIdx.x;
    int tl = tid >> 2;
    int h0 = (tid & 3) * 32;
    int t = t0 + tl;
    const u16* row = qkv + ((size_t)(b * T_ + t)) * (3 * D_);

#pragma unroll
    for (int u = 0; u < 4; ++u) {
        s16x8 raw = *reinterpret_cast<const s16x8*>(row + n * H_ + h0 + u * 8);
        s16x8 o;
#pragma unroll
        for (int e = 0; e < 8; ++e) o[e] = (short)f2bf(bf2f((u16)raw[e]) * SCALE);
        *reinterpret_cast<s16x8*>(qs + ((size_t)hn * T_ + t) * H_ + h0 + u * 8) = o;
    }

    float cbuf[16], sbuf[16];
    const float* cr = cosT + (size_t)t * F_ + h0 / 2;
    const float* sr = sinT + (size_t)t * F_ + h0 / 2;
#pragma unroll
    for (int u = 0; u < 4; ++u) {
        float4 c4 = *reinterpret_cast<const float4*>(cr + u * 4);
        float4 s4 = *reinterpret_cast<const float4*>(sr + u * 4);
        cbuf[u * 4 + 0] = c4.x; cbuf[u * 4 + 1] = c4.y; cbuf[u * 4 + 2] = c4.z; cbuf[u * 4 + 3] = c4.w;
        sbuf[u * 4 + 0] = s4.x; sbuf[u * 4 + 1] = s4.y; sbuf[u * 4 + 2] = s4.z; sbuf[u * 4 + 3] = s4.w;
    }

#pragma unroll
    for (int u = 0; u < 4; ++u) {
        s16x8 raw = *reinterpret_cast<const s16x8*>(row + D_ + n * H_ + h0 + u * 8);
        s16x8 o;
#pragma unroll
        for (int p = 0; p < 4; ++p) {
            float xr = bf2f((u16)raw[2 * p]), xi = bf2f((u16)raw[2 * p + 1]);
            float cc = cbuf[u * 4 + p], ss = sbuf[u * 4 + p];
            o[2 * p]     = (short)f2bf(xr * cc - xi * ss);
            o[2 * p + 1] = (short)f2bf(xr * ss + xi * cc);
        }
        *reinterpret_cast<s16x8*>(kr + ((size_t)hn * T_ + t) * H_ + h0 + u * 8) = o;
    }

#pragma unroll
    for (int u = 0; u < 4; ++u) {
        s16x8 raw = *reinterpret_cast<const s16x8*>(row + 2 * D_ + n * H_ + h0 + u * 8);
#pragma unroll
        for (int p = 0; p < 4; ++p) {
            float xr = bf2f((u16)raw[2 * p]), xi = bf2f((u16)raw[2 * p + 1]);
            float cc = cbuf[u * 4 + p], ss = sbuf[u * 4 + p];
            vtile[tl][h0 + u * 8 + 2 * p]     = f2bf(xr * cc - xi * ss);
            vtile[tl][h0 + u * 8 + 2 * p + 1] = f2bf(xr * ss + xi * cc);
        }
    }
    __syncthreads();

    int hrow = tid >> 1;
    int th = (tid & 1) * 32;
    u16 tmp[32];
#pragma unroll
    for (int i = 0; i < 32; ++i) tmp[i] = vtile[th + i][hrow];
    u16* dst = vt + ((size_t)(hn * H_ + hrow)) * T_ + t0 + th;
#pragma unroll
    for (int u = 0; u < 4; ++u) {
        s16x8 o;
#pragma unroll
        for (int e = 0; e < 8; ++e) o[e] = (short)tmp[u * 8 + e];
        *reinterpret_cast<s16x8*>(dst + u * 8) = o;
    }
}

// ---------------- flash attention (causal), LDS-staged K/V ----------------
// Block: 128 q rows (4 waves x 2 row-blocks of 16, interleaved), KV tiles of 64.
// qs [BN][T][H] (pre-scaled), kr [BN][T][H], vt [BN][H][T] -> ob [B*T][D] bf16
__global__ __launch_bounds__(256, 2) void attn_fwd(const u16* __restrict__ qs,
                                                   const u16* __restrict__ kr,
                                                   const u16* __restrict__ vt,
                                                   u16* __restrict__ ob) {
    // K tile: [64][128] bf16, XOR-swizzled (byte ^= (row&7)<<4), 16KB x2
    // V tile: [128][64] bf16, XOR-swizzled, 16KB x2
    // P: per-wave per-rowblock [16][64], XOR-swizzled, 16KB
    __shared__ __align__(16) u16 Ks[2][8192];
    __shared__ __align__(16) u16 Vs[2][8192];
    __shared__ __align__(16) u16 plds[4][2][1024];

    const int wave = threadIdx.x >> 6, lane = threadIdx.x & 63;
    const int g = lane >> 4, c0 = lane & 15;

    // XCD-aware swizzle (512 = 8*64, bijective) + long-blocks-first
    const int wg = blockIdx.x;
    const int orig = (wg & 7) * 64 + (wg >> 3);
    const int hn = orig >> 4;            // head index b*16+n
    const int qt = orig & 15;
    const int bq0 = (15 - qt) * 128;     // long blocks dispatched first

    const u16* qh = qs + (size_t)hn * T_ * H_;
    const u16* kh = kr + (size_t)hn * T_ * H_;
    const u16* vh = vt + (size_t)hn * H_ * T_;

    const int q0[2] = { bq0 + wave * 16, bq0 + 64 + wave * 16 };

    // Q fragments held in registers for the whole loop
    bf16x8 qf[2][4];
#pragma unroll
    for (int i = 0; i < 2; ++i)
#pragma unroll
        for (int kf = 0; kf < 4; ++kf)
            qf[i][kf] = ld8(qh + (size_t)(q0[i] + c0) * H_ + kf * 32 + g * 8);

    f32x4 o[2][8] = {};
    float m[2][4], l[2][4];
#pragma unroll
    for (int i = 0; i < 2; ++i)
#pragma unroll
        for (int r = 0; r < 4; ++r) { m[i][r] = -1e30f; l[i][r] = 0.0f; }

    const int nt = bq0 / 64 + 2;

    // stage KV tile t into buffer buf (pre-swizzled global source, linear LDS dest)
    auto stage = [&](int buf, int t) {
        const int kv0 = t * 64;
#pragma unroll
        for (int j = 0; j < 4; ++j) {
            // K: rows wave*16 + j*4 + lane/16, 16B chunk (lane&15)*16 bytes
            int ra = wave * 16 + j * 4 + (lane >> 4);
            int ca = ((lane & 15) * 8) ^ ((ra & 7) << 3);     // u16 units
            gload_lds16(kh + (size_t)(kv0 + ra) * H_ + ca, &Ks[buf][wave * 2048 + j * 512]);
            // V: rows wave*32 + j*8 + lane/8, 16B chunk (lane&7)*16 bytes
            int rv = wave * 32 + j * 8 + (lane >> 3);
            int cv = ((lane & 7) * 8) ^ ((rv & 7) << 3);      // u16 units
            gload_lds16(vh + (size_t)rv * T_ + kv0 + cv, &Vs[buf][wave * 2048 + j * 512]);
        }
    };

    stage(0, 0);
    __syncthreads();

    for (int t = 0; t < nt; ++t) {
        const int cur = t & 1;
        const int kv0 = t * 64;
        if (t + 1 < nt) stage(cur ^ 1, t + 1);

        const bool a0 = kv0 < q0[0] + 16;
        const bool a1 = kv0 < q0[1] + 16;

        // ---- S = Q K^T (both row-blocks share K fragments) ----
        f32x4 s[2][4] = {};
#pragma unroll
        for (int cc = 0; cc < 4; ++cc) {
            const int krow = cc * 16 + c0;
#pragma unroll
            for (int kf = 0; kf < 4; ++kf) {
                bf16x8 kfr = ld8(&Ks[cur][krow * 128 + ((kf * 32 + g * 8) ^ ((krow & 7) << 3))]);
                if (a0) s[0][cc] = mfma16(qf[0][kf], kfr, s[0][cc]);
                if (a1) s[1][cc] = mfma16(qf[1][kf], kfr, s[1][cc]);
            }
        }

        bf16x8 pa[2][2];
#pragma unroll
        for (int i = 0; i < 2; ++i) {
            const bool act = i ? a1 : a0;
            if (!act) continue;
            // ---- causal mask ----
            if (kv0 + 63 > q0[i]) {
#pragma unroll
                for (int cc = 0; cc < 4; ++cc) {
                    int col = kv0 + cc * 16 + c0;
#pragma unroll
                    for (int r = 0; r < 4; ++r)
                        if (col > q0[i] + g * 4 + r) s[i][cc][r] = -1e30f;
                }
            }
            // ---- online softmax (16-lane butterfly) ----
            float pm[4];
#pragma unroll
            for (int r = 0; r < 4; ++r)
                pm[r] = fmaxf(fmaxf(s[i][0][r], s[i][1][r]), fmaxf(s[i][2][r], s[i][3][r]));
#pragma unroll
            for (int r = 0; r < 4; ++r) {
                pm[r] = fmaxf(pm[r], __shfl_xor(pm[r], 1));
                pm[r] = fmaxf(pm[r], __shfl_xor(pm[r], 2));
                pm[r] = fmaxf(pm[r], __shfl_xor(pm[r], 4));
                pm[r] = fmaxf(pm[r], __shfl_xor(pm[r], 8));
            }
            float al[4], rs[4];
#pragma unroll
            for (int r = 0; r < 4; ++r) {
                float mn = fmaxf(m[i][r], pm[r]);
                al[r] = __expf(m[i][r] - mn);
                m[i][r] = mn;
                rs[r] = 0.0f;
            }
#pragma unroll
            for (int cc = 0; cc < 4; ++cc)
#pragma unroll
                for (int r = 0; r < 4; ++r) {
                    float p = __expf(s[i][cc][r] - m[i][r]);
                    s[i][cc][r] = p;
                    rs[r] += p;
                }
#pragma unroll
            for (int r = 0; r < 4; ++r) {
                rs[r] += __shfl_xor(rs[r], 1);
                rs[r] += __shfl_xor(rs[r], 2);
                rs[r] += __shfl_xor(rs[r], 4);
                rs[r] += __shfl_xor(rs[r], 8);
                l[i][r] = l[i][r] * al[r] + rs[r];
            }
#pragma unroll
            for (int hf = 0; hf < 8; ++hf)
#pragma unroll
                for (int r = 0; r < 4; ++r) o[i][hf][r] *= al[r];

            // ---- P -> swizzled LDS (C-layout write), read back in A-layout ----
            u16* pw = &plds[wave][i][0];
#pragma unroll
            for (int cc = 0; cc < 4; ++cc)
#pragma unroll
                for (int r = 0; r < 4; ++r) {
                    int prow = g * 4 + r;
                    pw[prow * 64 + ((cc * 16 + c0) ^ ((prow & 7) << 3))] = f2bf(s[i][cc][r]);
                }
#pragma unroll
            for (int kf2 = 0; kf2 < 2; ++kf2)
                pa[i][kf2] = ld8(&pw[c0 * 64 + ((kf2 * 32 + g * 8) ^ ((c0 & 7) << 3))]);
        }

        // ---- O += P V (both row-blocks share V fragments) ----
#pragma unroll
        for (int hf = 0; hf < 8; ++hf) {
            const int vrow = hf * 16 + c0;
#pragma unroll
            for (int kf2 = 0; kf2 < 2; ++kf2) {
                bf16x8 vfr = ld8(&Vs[cur][vrow * 64 + ((kf2 * 32 + g * 8) ^ ((vrow & 7) << 3))]);
                if (a0) o[0][hf] = mfma16(pa[0][kf2], vfr, o[0][hf]);
                if (a1) o[1][hf] = mfma16(pa[1][kf2], vfr, o[1][hf]);
            }
        }
        __syncthreads();
    }

    // ---- epilogue: normalize, write [B*T][D] bf16 ----
    const int bb = hn >> 4, nn = hn & 15;
#pragma unroll
    for (int i = 0; i < 2; ++i) {
        float inv[4];
#pragma unroll
        for (int r = 0; r < 4; ++r) inv[r] = 1.0f / l[i][r];
#pragma unroll
        for (int hf = 0; hf < 8; ++hf)
#pragma unroll
            for (int r = 0; r < 4; ++r) {
                int t = q0[i] + g * 4 + r;
                ob[((size_t)(bb * T_ + t)) * D_ + nn * H_ + hf * 16 + c0] = f2bf(o[i][hf][r] * inv[r]);
            }
    }
}

// ---------------- launch ----------------
extern "C" void kernel_launch(void* const* d_in, const int* in_sizes, int n_in,
                              void* d_out, int out_size, void* d_ws, size_t ws_size,
                              hipStream_t stream) {
    const float* x      = (const float*)d_in[0];
    const float* cosT   = (const float*)d_in[2];
    const float* sinT   = (const float*)d_in[3];
    const float* w_attn = (const float*)d_in[4];
    const float* w_out  = (const float*)d_in[5];
    float* out = (float*)d_out;

    char* ws = (char*)d_ws;
    u16* xb  = (u16*)(ws + 0);                  // x bf16            [4096][2048]
    u16* wat = (u16*)(ws + 16777216);           // w_attn^T bf16     [6144][2048]
    u16* wot = (u16*)(ws + 41943040);           // w_out^T bf16      [2048][2048]
    u16* qkv = (u16*)(ws + 50331648);           // qkv bf16          [4096][6144]
    u16* qsb = (u16*)(ws + 100663296);          // q scaled          [32][2048][128]
    u16* krb = (u16*)(ws + 117440512);          // k rope            [32][2048][128]
    u16* vtb = (u16*)(ws + 134217728);          // v rope transposed [32][128][2048]
    u16* obf = (u16*)(ws + 0);                  // attn out bf16 (reuses xb)

    cvt_bf16<<<(B_ * T_ * D_) / (256 * 8), 256, 0, stream>>>(x, xb, B_ * T_ * D_);
    transpose_cvt<<<dim3(3 * D_ / 64, D_ / 64), 256, 0, stream>>>(w_attn, wat, D_, 3 * D_);
    transpose_cvt<<<dim3(D_ / 64, D_ / 64), 256, 0, stream>>>(w_out, wot, D_, D_);
    gemm_bt<<<dim3(3 * D_ / BN, B_ * T_ / BM), 256, 0, stream>>>(xb, wat, qkv, nullptr,
                                                                 B_ * T_, 3 * D_, D_, 0);
    rope_split<<<B_ * N_ * (T_ / 64), 256, 0, stream>>>(qkv, cosT, sinT, qsb, krb, vtb);
    attn_fwd<<<B_ * N_ * (T_ / 128), 256, 0, stream>>>(qsb, krb, vtb, obf);
    gemm_bt<<<dim3(D_ / BN, B_ * T_ / BM), 256, 0, stream>>>(obf, wot, nullptr, out,
                                                             B_ * T_, D_, D_, 1);
}

// Round 3
// 328.281 us; speedup vs baseline: 2.7972x; 1.1257x over previous
//
#include <hip/hip_runtime.h>

typedef unsigned short u16;
typedef unsigned int u32;

#define B_ 2
#define T_ 2048
#define D_ 2048
#define N_ 16
#define H_ 128
#define F_ 64
// 1/sqrt(128) * log2(e)  -- log2e folded so softmax uses v_exp_f32 (2^x) directly
#define QSCALE 0.12751743226f

typedef __attribute__((ext_vector_type(8))) __bf16 bf16x8;
typedef __attribute__((ext_vector_type(8))) short s16x8;
typedef __attribute__((ext_vector_type(4))) float f32x4;
typedef __attribute__((ext_vector_type(4))) u16 u16x4;
typedef __attribute__((ext_vector_type(4))) u32 u32x4;

__device__ inline u16 f2bf(float f) {
    union { float f; u32 u; } v; v.f = f;
    u32 u = v.u;
    u32 r = (u + 0x7FFFu + ((u >> 16) & 1u)) >> 16;
    return (u16)r;
}
__device__ inline float bf2f(u16 h) {
    union { u32 u; float f; } v; v.u = ((u32)h) << 16;
    return v.f;
}
__device__ inline bf16x8 ld8(const u16* p) {
    s16x8 r = *reinterpret_cast<const s16x8*>(p);
    return __builtin_bit_cast(bf16x8, r);
}
__device__ inline f32x4 mfma16(bf16x8 a, bf16x8 b, f32x4 c) {
    return __builtin_amdgcn_mfma_f32_16x16x32_bf16(a, b, c, 0, 0, 0);
}
__device__ inline void gload_lds16(const u16* g, u16* l) {
    __builtin_amdgcn_global_load_lds(
        (const __attribute__((address_space(1))) void*)g,
        (__attribute__((address_space(3))) void*)l, 16, 0, 0);
}
__device__ inline float exp2fast(float x) {
    float r;
    asm("v_exp_f32 %0, %1" : "=v"(r) : "v"(x));
    return r;
}
__device__ inline u32 cvtpk(float lo, float hi) {
    u32 r;
    asm("v_cvt_pk_bf16_f32 %0, %1, %2" : "=v"(r) : "v"(lo), "v"(hi));
    return r;
}

// ---------------- convert f32 -> bf16 (straight) ----------------
__global__ __launch_bounds__(256) void cvt_bf16(const float* __restrict__ in,
                                                u16* __restrict__ out, int n) {
    int i = (blockIdx.x * 256 + threadIdx.x) * 8;
    if (i >= n) return;
    float4 a = *reinterpret_cast<const float4*>(in + i);
    float4 b = *reinterpret_cast<const float4*>(in + i + 4);
    s16x8 o;
    o[0] = (short)f2bf(a.x); o[1] = (short)f2bf(a.y);
    o[2] = (short)f2bf(a.z); o[3] = (short)f2bf(a.w);
    o[4] = (short)f2bf(b.x); o[5] = (short)f2bf(b.y);
    o[6] = (short)f2bf(b.z); o[7] = (short)f2bf(b.w);
    *reinterpret_cast<s16x8*>(out + i) = o;
}

// ---------------- transpose+convert: in[K][Nc] f32 -> out[Nc][K] bf16 ----------------
__global__ __launch_bounds__(256) void transpose_cvt(const float* __restrict__ in,
                                                     u16* __restrict__ out,
                                                     int K, int Nc) {
    __shared__ float tile[64][65];
    int n0 = blockIdx.x * 64, k0 = blockIdx.y * 64;
    int tid = threadIdx.x;
    int rr = tid >> 4;
    int cc = (tid & 15) * 4;
#pragma unroll
    for (int it = 0; it < 4; ++it) {
        int kk = it * 16 + rr;
        float4 v = *reinterpret_cast<const float4*>(in + (size_t)(k0 + kk) * Nc + n0 + cc);
        tile[kk][cc] = v.x; tile[kk][cc + 1] = v.y; tile[kk][cc + 2] = v.z; tile[kk][cc + 3] = v.w;
    }
    __syncthreads();
#pragma unroll
    for (int it = 0; it < 4; ++it) {
        int nn = it * 16 + rr;
        u16x4 o;
#pragma unroll
        for (int j = 0; j < 4; ++j) o[j] = f2bf(tile[cc + j][nn]);
        *reinterpret_cast<u16x4*>(out + (size_t)(n0 + nn) * K + k0 + cc) = o;
    }
}

// ---------------- GEMM: C[M][Nn] = A[M][K] * Bt[Nn][K]^T ----------------
#define BM 128
#define BN 128
#define BKg 32

__global__ __launch_bounds__(256) void gemm_bt(const u16* __restrict__ A,
                                               const u16* __restrict__ Bt,
                                               u16* __restrict__ Cb,
                                               float* __restrict__ Cf,
                                               int M, int Nn, int K, int out_f32) {
    __shared__ __align__(16) u16 As[2][BM * BKg];
    __shared__ __align__(16) u16 Bs[2][BM * BKg];
    const int tid = threadIdx.x;
    const int wave = tid >> 6, lane = tid & 63;
    const int m0 = blockIdx.y * BM, n0 = blockIdx.x * BN;
    const int lrow = lane >> 2, lcol = (lane & 3) * 8;
    const int wr = (wave >> 1) * 64, wc = (wave & 1) * 64;
    const int g = lane >> 4, c0 = lane & 15;

    f32x4 acc[4][4] = {};

    const int NT = K / BKg;

    auto stage = [&](int buf, int kt) {
        const int k0 = kt * BKg;
#pragma unroll
        for (int j = 0; j < 2; ++j) {
            const int c = wave + j * 4;
            gload_lds16(A + (size_t)(m0 + c * 16 + lrow) * K + k0 + lcol, &As[buf][c * 512]);
            gload_lds16(Bt + (size_t)(n0 + c * 16 + lrow) * K + k0 + lcol, &Bs[buf][c * 512]);
        }
    };

    stage(0, 0);
    __syncthreads();

    for (int t = 0; t < NT; ++t) {
        const int cur = t & 1;
        if (t + 1 < NT) stage(cur ^ 1, t + 1);
        bf16x8 af[4], bfr[4];
#pragma unroll
        for (int i = 0; i < 4; ++i) {
            af[i]  = ld8(&As[cur][(wr + i * 16 + c0) * BKg + g * 8]);
            bfr[i] = ld8(&Bs[cur][(wc + i * 16 + c0) * BKg + g * 8]);
        }
#pragma unroll
        for (int i = 0; i < 4; ++i)
#pragma unroll
            for (int j = 0; j < 4; ++j)
                acc[i][j] = mfma16(af[i], bfr[j], acc[i][j]);
        __syncthreads();
    }

#pragma unroll
    for (int i = 0; i < 4; ++i)
#pragma unroll
        for (int j = 0; j < 4; ++j)
#pragma unroll
            for (int r = 0; r < 4; ++r) {
                int row = m0 + wr + i * 16 + g * 4 + r;
                int col = n0 + wc + j * 16 + c0;
                float v = acc[i][j][r];
                if (out_f32) Cf[(size_t)row * Nn + col] = v;
                else         Cb[(size_t)row * Nn + col] = f2bf(v);
            }
}

// ---------------- RoPE + head-split + V-transpose ----------------
__global__ __launch_bounds__(256) void rope_split(const u16* __restrict__ qkv,
                                                  const float* __restrict__ cosT,
                                                  const float* __restrict__ sinT,
                                                  u16* __restrict__ qs,
                                                  u16* __restrict__ kr,
                                                  u16* __restrict__ vt) {
    __shared__ u16 vtile[64][129];
    int bi = blockIdx.x;
    int hn = bi >> 5;
    int tt = bi & 31;
    int b = hn >> 4, n = hn & 15;
    int t0 = tt * 64;
    int tid = threadIdx.x;
    int tl = tid >> 2;
    int h0 = (tid & 3) * 32;
    int t = t0 + tl;
    const u16* row = qkv + ((size_t)(b * T_ + t)) * (3 * D_);

#pragma unroll
    for (int u = 0; u < 4; ++u) {
        s16x8 raw = *reinterpret_cast<const s16x8*>(row + n * H_ + h0 + u * 8);
        s16x8 o;
#pragma unroll
        for (int e = 0; e < 8; ++e) o[e] = (short)f2bf(bf2f((u16)raw[e]) * QSCALE);
        *reinterpret_cast<s16x8*>(qs + ((size_t)hn * T_ + t) * H_ + h0 + u * 8) = o;
    }

    float cbuf[16], sbuf[16];
    const float* cr = cosT + (size_t)t * F_ + h0 / 2;
    const float* sr = sinT + (size_t)t * F_ + h0 / 2;
#pragma unroll
    for (int u = 0; u < 4; ++u) {
        float4 c4 = *reinterpret_cast<const float4*>(cr + u * 4);
        float4 s4 = *reinterpret_cast<const float4*>(sr + u * 4);
        cbuf[u * 4 + 0] = c4.x; cbuf[u * 4 + 1] = c4.y; cbuf[u * 4 + 2] = c4.z; cbuf[u * 4 + 3] = c4.w;
        sbuf[u * 4 + 0] = s4.x; sbuf[u * 4 + 1] = s4.y; sbuf[u * 4 + 2] = s4.z; sbuf[u * 4 + 3] = s4.w;
    }

#pragma unroll
    for (int u = 0; u < 4; ++u) {
        s16x8 raw = *reinterpret_cast<const s16x8*>(row + D_ + n * H_ + h0 + u * 8);
        s16x8 o;
#pragma unroll
        for (int p = 0; p < 4; ++p) {
            float xr = bf2f((u16)raw[2 * p]), xi = bf2f((u16)raw[2 * p + 1]);
            float cc = cbuf[u * 4 + p], ss = sbuf[u * 4 + p];
            o[2 * p]     = (short)f2bf(xr * cc - xi * ss);
            o[2 * p + 1] = (short)f2bf(xr * ss + xi * cc);
        }
        *reinterpret_cast<s16x8*>(kr + ((size_t)hn * T_ + t) * H_ + h0 + u * 8) = o;
    }

#pragma unroll
    for (int u = 0; u < 4; ++u) {
        s16x8 raw = *reinterpret_cast<const s16x8*>(row + 2 * D_ + n * H_ + h0 + u * 8);
#pragma unroll
        for (int p = 0; p < 4; ++p) {
            float xr = bf2f((u16)raw[2 * p]), xi = bf2f((u16)raw[2 * p + 1]);
            float cc = cbuf[u * 4 + p], ss = sbuf[u * 4 + p];
            vtile[tl][h0 + u * 8 + 2 * p]     = f2bf(xr * cc - xi * ss);
            vtile[tl][h0 + u * 8 + 2 * p + 1] = f2bf(xr * ss + xi * cc);
        }
    }
    __syncthreads();

    int hrow = tid >> 1;
    int th = (tid & 1) * 32;
    u16 tmp[32];
#pragma unroll
    for (int i = 0; i < 32; ++i) tmp[i] = vtile[th + i][hrow];
    u16* dst = vt + ((size_t)(hn * H_ + hrow)) * T_ + t0 + th;
#pragma unroll
    for (int u = 0; u < 4; ++u) {
        s16x8 o;
#pragma unroll
        for (int e = 0; e < 8; ++e) o[e] = (short)tmp[u * 8 + e];
        *reinterpret_cast<s16x8*>(dst + u * 8) = o;
    }
}

// ---------------- flash attention (causal), swapped-operand softmax ----------------
// S^T = mfma(K,Q): lane owns q-row c0, k spread over 4 g-lanes -> in-lane softmax,
// defer-max (THR=8), per-lane partial l, P redistributed via 16 bpermute.
__global__ __launch_bounds__(256, 2) void attn_fwd(const u16* __restrict__ qs,
                                                   const u16* __restrict__ kr,
                                                   const u16* __restrict__ vt,
                                                   u16* __restrict__ ob) {
    __shared__ __align__(16) u16 Ks[2][8192];
    __shared__ __align__(16) u16 Vs[2][8192];

    const int wave = threadIdx.x >> 6, lane = threadIdx.x & 63;
    const int g = lane >> 4, c0 = lane & 15;

    // XCD-aware swizzle (512 = 8*64, bijective) + long-blocks-first
    const int wg = blockIdx.x;
    const int orig = (wg & 7) * 64 + (wg >> 3);
    const int hn = orig >> 4;
    const int qt = orig & 15;
    const int bq0 = (15 - qt) * 128;

    const u16* qh = qs + (size_t)hn * T_ * H_;
    const u16* kh = kr + (size_t)hn * T_ * H_;
    const u16* vh = vt + (size_t)hn * H_ * T_;

    const int q0[2] = { bq0 + wave * 16, bq0 + 64 + wave * 16 };

    bf16x8 qf[2][4];
#pragma unroll
    for (int i = 0; i < 2; ++i)
#pragma unroll
        for (int kf = 0; kf < 4; ++kf)
            qf[i][kf] = ld8(qh + (size_t)(q0[i] + c0) * H_ + kf * 32 + g * 8);

    f32x4 o[2][8] = {};
    float m[2] = { -1e30f, -1e30f };   // row max (uniform across g-lanes), log2 units
    float l[2] = { 0.0f, 0.0f };       // per-lane PARTIAL row sum

    const int nt = bq0 / 64 + 2;

    auto stage = [&](int buf, int t) {
        const int kv0 = t * 64;
#pragma unroll
        for (int j = 0; j < 4; ++j) {
            int ra = wave * 16 + j * 4 + (lane >> 4);
            int ca = ((lane & 15) * 8) ^ ((ra & 7) << 3);
            gload_lds16(kh + (size_t)(kv0 + ra) * H_ + ca, &Ks[buf][wave * 2048 + j * 512]);
            int rv = wave * 32 + j * 8 + (lane >> 3);
            int cv = ((lane & 7) * 8) ^ ((rv & 7) << 3);
            gload_lds16(vh + (size_t)rv * T_ + kv0 + cv, &Vs[buf][wave * 2048 + j * 512]);
        }
    };

    stage(0, 0);
    __syncthreads();

    const int srcA = ((g & 1) * 2) * 16 + c0;   // bpermute source lanes
    const int srcB = srcA + 16;
    const int sel  = g >> 1;

    for (int t = 0; t < nt; ++t) {
        const int cur = t & 1;
        const int kv0 = t * 64;
        if (t + 1 < nt) stage(cur ^ 1, t + 1);

        const bool a0 = kv0 < q0[0] + 16;
        const bool a1 = kv0 < q0[1] + 16;

        // ---- S^T = K Q^T : lane -> q-col c0, k-rows cc*16 + g*4 + r ----
        f32x4 s[2][4] = {};
        __builtin_amdgcn_s_setprio(1);
#pragma unroll
        for (int cc = 0; cc < 4; ++cc) {
            const int krow = cc * 16 + c0;
#pragma unroll
            for (int kf = 0; kf < 4; ++kf) {
                bf16x8 kfr = ld8(&Ks[cur][krow * 128 + ((kf * 32 + g * 8) ^ ((krow & 7) << 3))]);
                if (a0) s[0][cc] = mfma16(kfr, qf[0][kf], s[0][cc]);
                if (a1) s[1][cc] = mfma16(kfr, qf[1][kf], s[1][cc]);
            }
        }
        __builtin_amdgcn_s_setprio(0);

        bf16x8 pb[2][2];
#pragma unroll
        for (int i = 0; i < 2; ++i) {
            const bool act = i ? a1 : a0;
            if (!act) continue;
            const int qrow = q0[i] + c0;
            // ---- causal mask (k > q) ----
            if (kv0 + 63 > q0[i]) {
#pragma unroll
                for (int cc = 0; cc < 4; ++cc) {
                    int kloc = kv0 + cc * 16 + g * 4;
#pragma unroll
                    for (int r = 0; r < 4; ++r)
                        if (kloc + r > qrow) s[i][cc][r] = -1e30f;
                }
            }
            // ---- in-lane max ----
            float pmax = s[i][0][0];
#pragma unroll
            for (int cc = 0; cc < 4; ++cc)
#pragma unroll
                for (int r = 0; r < 4; ++r) pmax = fmaxf(pmax, s[i][cc][r]);
            // ---- defer-max: rescale only if some row grew past m+8 ----
            if (!__all(pmax <= m[i] + 8.0f)) {
                pmax = fmaxf(pmax, __shfl_xor(pmax, 16));
                pmax = fmaxf(pmax, __shfl_xor(pmax, 32));
                float mn = fmaxf(m[i], pmax);
                float al = exp2fast(m[i] - mn);
                m[i] = mn;
                l[i] *= al;
#pragma unroll
                for (int hf = 0; hf < 8; ++hf)
#pragma unroll
                    for (int r = 0; r < 4; ++r) o[i][hf][r] *= al;
            }
            // ---- p = 2^(s-m), partial sum, pack to bf16 words ----
            u32 w[4][2];
#pragma unroll
            for (int cc = 0; cc < 4; ++cc) {
                float p0 = exp2fast(s[i][cc][0] - m[i]);
                float p1 = exp2fast(s[i][cc][1] - m[i]);
                float p2 = exp2fast(s[i][cc][2] - m[i]);
                float p3 = exp2fast(s[i][cc][3] - m[i]);
                l[i] += (p0 + p1) + (p2 + p3);
                w[cc][0] = cvtpk(p0, p1);
                w[cc][1] = cvtpk(p2, p3);
            }
            // ---- redistribute P^T -> B-operand fragments (16 bpermute) ----
#pragma unroll
            for (int ks2 = 0; ks2 < 2; ++ks2) {
                u32 r00 = __shfl(w[ks2 * 2 + 0][0], srcA);
                u32 r01 = __shfl(w[ks2 * 2 + 0][1], srcA);
                u32 r02 = __shfl(w[ks2 * 2 + 0][0], srcB);
                u32 r03 = __shfl(w[ks2 * 2 + 0][1], srcB);
                u32 r10 = __shfl(w[ks2 * 2 + 1][0], srcA);
                u32 r11 = __shfl(w[ks2 * 2 + 1][1], srcA);
                u32 r12 = __shfl(w[ks2 * 2 + 1][0], srcB);
                u32 r13 = __shfl(w[ks2 * 2 + 1][1], srcB);
                u32x4 wv;
                wv[0] = sel ? r10 : r00;
                wv[1] = sel ? r11 : r01;
                wv[2] = sel ? r12 : r02;
                wv[3] = sel ? r13 : r03;
                pb[i][ks2] = __builtin_bit_cast(bf16x8, wv);
            }
        }

        // ---- O^T += V^T P^T (V fragments shared by both rowblocks) ----
        __builtin_amdgcn_s_setprio(1);
#pragma unroll
        for (int hf = 0; hf < 8; ++hf) {
            const int vrow = hf * 16 + c0;
#pragma unroll
            for (int ks2 = 0; ks2 < 2; ++ks2) {
                bf16x8 vfr = ld8(&Vs[cur][vrow * 64 + ((ks2 * 32 + g * 8) ^ ((vrow & 7) << 3))]);
                if (a0) o[0][hf] = mfma16(vfr, pb[0][ks2], o[0][hf]);
                if (a1) o[1][hf] = mfma16(vfr, pb[1][ks2], o[1][hf]);
            }
        }
        __builtin_amdgcn_s_setprio(0);
        __syncthreads();
    }

    // ---- epilogue: reduce l across g-lanes, normalize, packed 8B stores ----
    const int bb = hn >> 4, nn = hn & 15;
#pragma unroll
    for (int i = 0; i < 2; ++i) {
        float lt = l[i] + __shfl_xor(l[i], 16);
        lt += __shfl_xor(lt, 32);
        float inv = 1.0f / lt;
        const size_t rowoff = ((size_t)(bb * T_ + q0[i] + c0)) * D_ + nn * H_ + g * 4;
#pragma unroll
        for (int hf = 0; hf < 8; ++hf) {
            u16x4 pk;
#pragma unroll
            for (int r = 0; r < 4; ++r) pk[r] = f2bf(o[i][hf][r] * inv);
            *reinterpret_cast<u16x4*>(ob + rowoff + hf * 16) = pk;
        }
    }
}

// ---------------- launch ----------------
extern "C" void kernel_launch(void* const* d_in, const int* in_sizes, int n_in,
                              void* d_out, int out_size, void* d_ws, size_t ws_size,
                              hipStream_t stream) {
    const float* x      = (const float*)d_in[0];
    const float* cosT   = (const float*)d_in[2];
    const float* sinT   = (const float*)d_in[3];
    const float* w_attn = (const float*)d_in[4];
    const float* w_out  = (const float*)d_in[5];
    float* out = (float*)d_out;

    char* ws = (char*)d_ws;
    u16* xb  = (u16*)(ws + 0);
    u16* wat = (u16*)(ws + 16777216);
    u16* wot = (u16*)(ws + 41943040);
    u16* qkv = (u16*)(ws + 50331648);
    u16* qsb = (u16*)(ws + 100663296);
    u16* krb = (u16*)(ws + 117440512);
    u16* vtb = (u16*)(ws + 134217728);
    u16* obf = (u16*)(ws + 0);

    cvt_bf16<<<(B_ * T_ * D_) / (256 * 8), 256, 0, stream>>>(x, xb, B_ * T_ * D_);
    transpose_cvt<<<dim3(3 * D_ / 64, D_ / 64), 256, 0, stream>>>(w_attn, wat, D_, 3 * D_);
    transpose_cvt<<<dim3(D_ / 64, D_ / 64), 256, 0, stream>>>(w_out, wot, D_, D_);
    gemm_bt<<<dim3(3 * D_ / BN, B_ * T_ / BM), 256, 0, stream>>>(xb, wat, qkv, nullptr,
                                                                 B_ * T_, 3 * D_, D_, 0);
    rope_split<<<B_ * N_ * (T_ / 64), 256, 0, stream>>>(qkv, cosT, sinT, qsb, krb, vtb);
    attn_fwd<<<B_ * N_ * (T_ / 128), 256, 0, stream>>>(qsb, krb, vtb, obf);
    gemm_bt<<<dim3(D_ / BN, B_ * T_ / BM), 256, 0, stream>>>(obf, wot, nullptr, out,
                                                             B_ * T_, D_, D_, 1);
}